// Round 1
// baseline (543.197 us; speedup 1.0000x reference)
//
#include <hip/hip_runtime.h>
#include <math.h>

#define NN 5000      // nodes
#define NE 40000     // edges
#define UU 64        // hidden units
#define FE 16        // edge features
#define FEP 17       // +1 pseudo-feature for edge_bias
#define KD (FEP*UU)  // 1088 = reduction dim of agg matmul
#define NSTEPS 4

__device__ __forceinline__ int rfl(int x){ return __builtin_amdgcn_readfirstlane(x); }

// Wt[(f*64+j)*64 + i] = EK[f, i*64+j]  (f<16);  row block f==16 gets edge_bias
__global__ void build_wt(const float* __restrict__ ek, const float* __restrict__ eb,
                         float* __restrict__ wt){
  int tid = blockIdx.x*blockDim.x + threadIdx.x;
  if (tid >= FEP*UU*UU) return;
  int f = tid >> 12;        // /4096
  int r = tid & 4095;       // i*64+j
  int j = r & 63;
  int i = r >> 6;
  float v = (f < FE) ? ek[f*4096 + r] : eb[r];
  wt[(f*64 + j)*64 + i] = v;
}

__global__ void hist_k(const int* __restrict__ pair, int* __restrict__ hist){
  int e = blockIdx.x*blockDim.x + threadIdx.x;
  if (e < NE) atomicAdd(&hist[pair[2*e]], 1);
}

// single-block exclusive scan of hist[0..NN-1]; writes offsets in place (aliases hist)
// and a copy into cursor. offsets[NN] = total = NE.
__global__ void scan_k(int* __restrict__ offs, int* __restrict__ cursor){
  __shared__ int s[1024];
  const int PER = 5;                      // 1024*5 = 5120 >= 5000
  int t = threadIdx.x;
  int base = t*PER;
  int loc[PER]; int sum = 0;
  #pragma unroll
  for (int q=0;q<PER;++q){ int idx = base+q; int v = (idx<NN)?offs[idx]:0; loc[q]=v; sum+=v; }
  s[t] = sum; __syncthreads();
  for (int off=1; off<1024; off<<=1){
    int v = (t>=off) ? s[t-off] : 0;
    __syncthreads();
    s[t] += v;
    __syncthreads();
  }
  int run = s[t] - sum;                   // exclusive prefix
  #pragma unroll
  for (int q=0;q<PER;++q){ int idx = base+q;
    if (idx<NN){ offs[idx]=run; cursor[idx]=run; run+=loc[q]; } }
  if (t==1023) offs[NN] = run;            // == NE
}

__global__ void scatter_k(const int* __restrict__ pair, int* __restrict__ cursor,
                          int* __restrict__ eid){
  int e = blockIdx.x*blockDim.x + threadIdx.x;
  if (e < NE){ int pos = atomicAdd(&cursor[pair[2*e]], 1); eid[pos] = e; }
}

// deterministic accumulation order: insertion-sort each node's edge sublist
__global__ void sortsub_k(const int* __restrict__ offs, int* __restrict__ eid){
  int v = blockIdx.x*blockDim.x + threadIdx.x;
  if (v >= NN) return;
  int b = offs[v], e = offs[v+1];
  for (int i=b+1; i<e; ++i){
    int key = eid[i]; int j = i-1;
    while (j>=b && eid[j]>key){ eid[j+1]=eid[j]; --j; }
    eid[j+1] = key;
  }
}

// one wave per node: G[v, f, j] = sum_{e:src=v} ef'[e,f] * h[nbr_e, j]
__global__ void gather_k(const float* __restrict__ h, const int* __restrict__ pair,
                         const float* __restrict__ ef, const int* __restrict__ offs,
                         const int* __restrict__ eid, float* __restrict__ G){
  int wid  = (blockIdx.x*blockDim.x + threadIdx.x) >> 6;
  int lane = threadIdx.x & 63;
  int v = rfl(wid);
  if (v >= NN) return;
  float g[FEP];
  #pragma unroll
  for (int f=0;f<FEP;++f) g[f] = 0.f;
  int b = offs[v], e2 = offs[v+1];
  for (int idx=b; idx<e2; ++idx){
    int e = rfl(eid[idx]);
    int nbr = pair[2*e+1];
    float hj = h[nbr*UU + lane];
    #pragma unroll
    for (int f=0; f<FE; ++f) g[f] = fmaf(ef[e*FE+f], hj, g[f]);
    g[FE] += hj;
  }
  #pragma unroll
  for (int f=0;f<FEP;++f) G[(size_t)v*KD + f*64 + lane] = g[f];
}

// agg = G (NN x KD) @ Wt (KD x 64); wave = 8 nodes, lane = output unit
#define MM_NV 8
__global__ void matmul_k(const float* __restrict__ G, const float* __restrict__ wt,
                         float* __restrict__ agg){
  int wid  = (blockIdx.x*blockDim.x + threadIdx.x) >> 6;
  int lane = threadIdx.x & 63;
  int vb = rfl(wid) * MM_NV;
  if (vb >= NN) return;
  float acc[MM_NV];
  #pragma unroll
  for (int t=0;t<MM_NV;++t) acc[t] = 0.f;
  for (int k=0; k<KD; k+=4){
    float w0 = wt[(k+0)*64 + lane];
    float w1 = wt[(k+1)*64 + lane];
    float w2 = wt[(k+2)*64 + lane];
    float w3 = wt[(k+3)*64 + lane];
    #pragma unroll
    for (int t=0;t<MM_NV;++t){
      const float4 g4 = *reinterpret_cast<const float4*>(&G[(size_t)(vb+t)*KD + k]);
      acc[t] = fmaf(g4.x,w0, fmaf(g4.y,w1, fmaf(g4.z,w2, fmaf(g4.w,w3, acc[t]))));
    }
  }
  #pragma unroll
  for (int t=0;t<MM_NV;++t) agg[(vb+t)*UU + lane] = acc[t];
}

// fused GRU cell; wave = 4 nodes, lane = unit u. Updates h in place.
#define GR_NV 4
__global__ void gru_k(const float* __restrict__ agg, float* __restrict__ h,
                      const float* __restrict__ gk, const float* __restrict__ rk,
                      const float* __restrict__ gb){
  int wid = (blockIdx.x*blockDim.x + threadIdx.x) >> 6;
  int u   = threadIdx.x & 63;
  int vb = rfl(wid) * GR_NV;
  if (vb >= NN) return;
  float xz[GR_NV]={0}, xr[GR_NV]={0}, xh[GR_NV]={0};
  float iz[GR_NV]={0}, ir[GR_NV]={0}, ih[GR_NV]={0};
  for (int k=0;k<UU;++k){
    float g0 = gk[k*192 + u], g1 = gk[k*192 + 64 + u], g2 = gk[k*192 + 128 + u];
    float r0 = rk[k*192 + u], r1 = rk[k*192 + 64 + u], r2 = rk[k*192 + 128 + u];
    #pragma unroll
    for (int t=0;t<GR_NV;++t){
      float a  = agg[(vb+t)*UU + k];
      float hk = h  [(vb+t)*UU + k];
      xz[t] = fmaf(a,g0,xz[t]); xr[t] = fmaf(a,g1,xr[t]); xh[t] = fmaf(a,g2,xh[t]);
      iz[t] = fmaf(hk,r0,iz[t]); ir[t] = fmaf(hk,r1,ir[t]); ih[t] = fmaf(hk,r2,ih[t]);
    }
  }
  float b0z = gb[u],     b0r = gb[64+u],  b0h = gb[128+u];
  float b1z = gb[192+u], b1r = gb[256+u], b1h = gb[320+u];
  #pragma unroll
  for (int t=0;t<GR_NV;++t){
    float z = 1.f/(1.f + expf(-(xz[t]+b0z + iz[t]+b1z)));
    float r = 1.f/(1.f + expf(-(xr[t]+b0r + ir[t]+b1r)));
    float hc = tanhf(xh[t]+b0h + r*(ih[t]+b1h));
    float hold = h[(vb+t)*UU + u];
    h[(vb+t)*UU + u] = z*hold + (1.f-z)*hc;
  }
}

extern "C" void kernel_launch(void* const* d_in, const int* in_sizes, int n_in,
                              void* d_out, int out_size, void* d_ws, size_t ws_size,
                              hipStream_t stream){
  const float* nodef = (const float*)d_in[0];
  const float* edgef = (const float*)d_in[1];
  const int*   pair  = (const int*)  d_in[2];
  const float* ek    = (const float*)d_in[3];
  const float* ebias = (const float*)d_in[4];
  const float* gk    = (const float*)d_in[5];
  const float* rk    = (const float*)d_in[6];
  const float* gb    = (const float*)d_in[7];

  char* ws = (char*)d_ws;
  size_t o = 0;
  auto carve = [&](size_t bytes)->char*{
    char* p = ws + o; o = (o + bytes + 255) & ~255ULL; return p; };
  int*   offs   = (int*)  carve((NN+1)*sizeof(int));   // hist, then offsets in place
  int*   cursor = (int*)  carve(NN*sizeof(int));
  int*   eid    = (int*)  carve(NE*sizeof(int));
  float* wt     = (float*)carve((size_t)KD*64*sizeof(float));
  float* G      = (float*)carve((size_t)NN*KD*sizeof(float));
  float* hbuf   = (float*)carve((size_t)NN*UU*sizeof(float));
  float* agg    = (float*)carve((size_t)NN*UU*sizeof(float));

  // --- per-launch preprocessing (deterministic) ---
  hipMemsetAsync(offs, 0, (NN+1)*sizeof(int), stream);
  build_wt <<<(FEP*4096+255)/256, 256, 0, stream>>>(ek, ebias, wt);
  hist_k   <<<(NE+255)/256,       256, 0, stream>>>(pair, offs);
  scan_k   <<<1, 1024, 0, stream>>>(offs, cursor);
  scatter_k<<<(NE+255)/256,       256, 0, stream>>>(pair, cursor, eid);
  sortsub_k<<<(NN+255)/256,       256, 0, stream>>>(offs, eid);
  hipMemcpyAsync(hbuf, nodef, (size_t)NN*UU*sizeof(float),
                 hipMemcpyDeviceToDevice, stream);

  // --- message-passing steps ---
  for (int s=0; s<NSTEPS; ++s){
    gather_k<<<(NN*64)/256, 256, 0, stream>>>(hbuf, pair, edgef, offs, eid, G);
    {
      int waves = (NN + MM_NV - 1)/MM_NV;          // 625
      int blocks = (waves*64 + 255)/256;           // 157
      matmul_k<<<blocks, 256, 0, stream>>>(G, wt, agg);
    }
    {
      int waves = (NN + GR_NV - 1)/GR_NV;          // 1250
      int blocks = (waves*64 + 255)/256;           // 313
      gru_k<<<blocks, 256, 0, stream>>>(agg, hbuf, gk, rk, gb);
    }
  }
  hipMemcpyAsync(d_out, hbuf, (size_t)NN*UU*sizeof(float),
                 hipMemcpyDeviceToDevice, stream);
}

// Round 2
// 262.447 us; speedup vs baseline: 2.0697x; 2.0697x over previous
//
#include <hip/hip_runtime.h>
#include <math.h>

#define NN 5000      // nodes
#define NNP 5008     // padded to 16
#define NE 40000     // edges
#define UU 64        // hidden units
#define FE 16        // edge features
#define FEP 17       // +1 pseudo-feature for edge_bias
#define KD (FEP*UU)  // 1088 = reduction dim of agg matmul
#define NSTEPS 4

typedef _Float16 half8 __attribute__((ext_vector_type(8)));
typedef float f32x4 __attribute__((ext_vector_type(4)));

__device__ __forceinline__ int rfl(int x){ return __builtin_amdgcn_readfirstlane(x); }

// Wb[i*1088 + k] = (f<16 ? ek[f,i*64+j] : eb[i*64+j]),  k=f*64+j   (B^T layout, f16)
__global__ void build_wb(const float* __restrict__ ek, const float* __restrict__ eb,
                         _Float16* __restrict__ wb){
  int tid = blockIdx.x*blockDim.x + threadIdx.x;
  if (tid >= UU*KD) return;
  int i = tid / KD;
  int k = tid - i*KD;
  int f = k >> 6, j = k & 63;
  float v = (f < FE) ? ek[f*4096 + i*64 + j] : eb[i*64 + j];
  wb[(size_t)i*KD + k] = (_Float16)v;
}

__global__ void hist_k(const int* __restrict__ pair, int* __restrict__ hist){
  int e = blockIdx.x*blockDim.x + threadIdx.x;
  if (e < NE) atomicAdd(&hist[pair[2*e]], 1);
}

// single-block exclusive scan; offsets in place; copy to cursor. offs[NN]=NE.
__global__ void scan_k(int* __restrict__ offs, int* __restrict__ cursor){
  __shared__ int s[1024];
  const int PER = 5;
  int t = threadIdx.x;
  int base = t*PER;
  int loc[PER]; int sum = 0;
  #pragma unroll
  for (int q=0;q<PER;++q){ int idx = base+q; int v = (idx<NN)?offs[idx]:0; loc[q]=v; sum+=v; }
  s[t] = sum; __syncthreads();
  for (int off=1; off<1024; off<<=1){
    int v = (t>=off) ? s[t-off] : 0;
    __syncthreads();
    s[t] += v;
    __syncthreads();
  }
  int run = s[t] - sum;
  #pragma unroll
  for (int q=0;q<PER;++q){ int idx = base+q;
    if (idx<NN){ offs[idx]=run; cursor[idx]=run; run+=loc[q]; } }
  if (t==1023) offs[NN] = run;
}

__global__ void scatter_k(const int* __restrict__ pair, int* __restrict__ cursor,
                          int* __restrict__ eid){
  int e = blockIdx.x*blockDim.x + threadIdx.x;
  if (e < NE){ int pos = atomicAdd(&cursor[pair[2*e]], 1); eid[pos] = e; }
}

// deterministic accumulation order: insertion-sort each node's edge sublist
__global__ void sortsub_k(const int* __restrict__ offs, int* __restrict__ eid){
  int v = blockIdx.x*blockDim.x + threadIdx.x;
  if (v >= NN) return;
  int b = offs[v], e = offs[v+1];
  for (int i=b+1; i<e; ++i){
    int key = eid[i]; int j = i-1;
    while (j>=b && eid[j]>key){ eid[j+1]=eid[j]; --j; }
    eid[j+1] = key;
  }
}

// one wave per node: G[v, f*64+j] = sum_{e:src=v} ef'[e,f] * h[nbr_e, j]  (f16 out)
__global__ void gather_k(const float* __restrict__ h, const int* __restrict__ pair,
                         const float* __restrict__ ef, const int* __restrict__ offs,
                         const int* __restrict__ eid, _Float16* __restrict__ G){
  int wid  = (blockIdx.x*blockDim.x + threadIdx.x) >> 6;
  int lane = threadIdx.x & 63;
  int v = rfl(wid);
  if (v >= NN) return;
  float g[FEP];
  #pragma unroll
  for (int f=0;f<FEP;++f) g[f] = 0.f;
  int b = offs[v], e2 = offs[v+1];
  for (int idx=b; idx<e2; ++idx){
    int e = rfl(eid[idx]);
    int nbr = pair[2*e+1];
    float hj = h[nbr*UU + lane];
    #pragma unroll
    for (int f=0; f<FE; ++f) g[f] = fmaf(ef[e*FE+f], hj, g[f]);
    g[FE] += hj;
  }
  #pragma unroll
  for (int f=0;f<FEP;++f) G[(size_t)v*KD + f*64 + lane] = (_Float16)g[f];
}

// agg(NNP x 64) = G(NNP x 1088, f16) @ Wb^T(1088 x 64, f16), MFMA 16x16x32
// one wave per 16-node M-tile; 4 column fragments; 34 k-steps; f32 accum.
__global__ void matmul_f16(const _Float16* __restrict__ G, const _Float16* __restrict__ wb,
                           float* __restrict__ agg){
  int wid  = (blockIdx.x*blockDim.x + threadIdx.x) >> 6;
  int lane = threadIdx.x & 63;
  int vb = rfl(wid) * 16;
  if (vb >= NNP) return;
  int r16 = lane & 15, kh = lane >> 4;            // kh in 0..3
  const _Float16* arow = G  + (size_t)(vb + r16)*KD + kh*8;
  const _Float16* b0p  = wb + (size_t)(r16 +  0)*KD + kh*8;
  const _Float16* b1p  = wb + (size_t)(r16 + 16)*KD + kh*8;
  const _Float16* b2p  = wb + (size_t)(r16 + 32)*KD + kh*8;
  const _Float16* b3p  = wb + (size_t)(r16 + 48)*KD + kh*8;
  f32x4 acc0 = {0,0,0,0}, acc1 = {0,0,0,0}, acc2 = {0,0,0,0}, acc3 = {0,0,0,0};
  #pragma unroll 2
  for (int k0 = 0; k0 < KD; k0 += 32){
    half8 a  = *(const half8*)(arow + k0);
    half8 b0 = *(const half8*)(b0p  + k0);
    half8 b1 = *(const half8*)(b1p  + k0);
    half8 b2 = *(const half8*)(b2p  + k0);
    half8 b3 = *(const half8*)(b3p  + k0);
    acc0 = __builtin_amdgcn_mfma_f32_16x16x32_f16(a, b0, acc0, 0, 0, 0);
    acc1 = __builtin_amdgcn_mfma_f32_16x16x32_f16(a, b1, acc1, 0, 0, 0);
    acc2 = __builtin_amdgcn_mfma_f32_16x16x32_f16(a, b2, acc2, 0, 0, 0);
    acc3 = __builtin_amdgcn_mfma_f32_16x16x32_f16(a, b3, acc3, 0, 0, 0);
  }
  // C layout: col = lane&15, row = (lane>>4)*4 + r
  #pragma unroll
  for (int r = 0; r < 4; ++r){
    int row = vb + kh*4 + r;
    if (row < NN){
      float* o = agg + (size_t)row*UU + r16;
      o[ 0] = acc0[r];
      o[16] = acc1[r];
      o[32] = acc2[r];
      o[48] = acc3[r];
    }
  }
}

// fused GRU cell; wave = 4 nodes, lane = unit u. Updates h in place.
#define GR_NV 4
__global__ void gru_k(const float* __restrict__ agg, float* __restrict__ h,
                      const float* __restrict__ gk, const float* __restrict__ rk,
                      const float* __restrict__ gb){
  int wid = (blockIdx.x*blockDim.x + threadIdx.x) >> 6;
  int u   = threadIdx.x & 63;
  int vb = rfl(wid) * GR_NV;
  if (vb >= NN) return;
  float xz[GR_NV]={0}, xr[GR_NV]={0}, xh[GR_NV]={0};
  float iz[GR_NV]={0}, ir[GR_NV]={0}, ih[GR_NV]={0};
  for (int k=0;k<UU;++k){
    float g0 = gk[k*192 + u], g1 = gk[k*192 + 64 + u], g2 = gk[k*192 + 128 + u];
    float r0 = rk[k*192 + u], r1 = rk[k*192 + 64 + u], r2 = rk[k*192 + 128 + u];
    #pragma unroll
    for (int t=0;t<GR_NV;++t){
      float a  = agg[(vb+t)*UU + k];
      float hk = h  [(vb+t)*UU + k];
      xz[t] = fmaf(a,g0,xz[t]); xr[t] = fmaf(a,g1,xr[t]); xh[t] = fmaf(a,g2,xh[t]);
      iz[t] = fmaf(hk,r0,iz[t]); ir[t] = fmaf(hk,r1,ir[t]); ih[t] = fmaf(hk,r2,ih[t]);
    }
  }
  float b0z = gb[u],     b0r = gb[64+u],  b0h = gb[128+u];
  float b1z = gb[192+u], b1r = gb[256+u], b1h = gb[320+u];
  #pragma unroll
  for (int t=0;t<GR_NV;++t){
    float z = 1.f/(1.f + expf(-(xz[t]+b0z + iz[t]+b1z)));
    float r = 1.f/(1.f + expf(-(xr[t]+b0r + ir[t]+b1r)));
    float hc = tanhf(xh[t]+b0h + r*(ih[t]+b1h));
    float hold = h[(vb+t)*UU + u];
    h[(vb+t)*UU + u] = z*hold + (1.f-z)*hc;
  }
}

extern "C" void kernel_launch(void* const* d_in, const int* in_sizes, int n_in,
                              void* d_out, int out_size, void* d_ws, size_t ws_size,
                              hipStream_t stream){
  const float* nodef = (const float*)d_in[0];
  const float* edgef = (const float*)d_in[1];
  const int*   pair  = (const int*)  d_in[2];
  const float* ek    = (const float*)d_in[3];
  const float* ebias = (const float*)d_in[4];
  const float* gk    = (const float*)d_in[5];
  const float* rk    = (const float*)d_in[6];
  const float* gb    = (const float*)d_in[7];

  char* ws = (char*)d_ws;
  size_t o = 0;
  auto carve = [&](size_t bytes)->char*{
    char* p = ws + o; o = (o + bytes + 255) & ~255ULL; return p; };
  int*      offs   = (int*)     carve((NN+1)*sizeof(int));
  int*      cursor = (int*)     carve(NN*sizeof(int));
  int*      eid    = (int*)     carve(NE*sizeof(int));
  _Float16* wb     = (_Float16*)carve((size_t)UU*KD*sizeof(_Float16));
  _Float16* G      = (_Float16*)carve((size_t)NNP*KD*sizeof(_Float16));
  float*    hbuf   = (float*)   carve((size_t)NN*UU*sizeof(float));
  float*    agg    = (float*)   carve((size_t)NN*UU*sizeof(float));

  // --- per-launch preprocessing (deterministic) ---
  hipMemsetAsync(offs, 0, (NN+1)*sizeof(int), stream);
  build_wb <<<(UU*KD+255)/256, 256, 0, stream>>>(ek, ebias, wb);
  hist_k   <<<(NE+255)/256,    256, 0, stream>>>(pair, offs);
  scan_k   <<<1, 1024, 0, stream>>>(offs, cursor);
  scatter_k<<<(NE+255)/256,    256, 0, stream>>>(pair, cursor, eid);
  sortsub_k<<<(NN+255)/256,    256, 0, stream>>>(offs, eid);
  hipMemcpyAsync(hbuf, nodef, (size_t)NN*UU*sizeof(float),
                 hipMemcpyDeviceToDevice, stream);

  // --- message-passing steps ---
  for (int s=0; s<NSTEPS; ++s){
    gather_k<<<(NN*64)/256, 256, 0, stream>>>(hbuf, pair, edgef, offs, eid, G);
    {
      int waves  = NNP/16;                       // 313
      int blocks = (waves*64 + 255)/256;         // 79
      matmul_f16<<<blocks, 256, 0, stream>>>(G, wb, agg);
    }
    {
      int waves = (NN + GR_NV - 1)/GR_NV;        // 1250
      int blocks = (waves*64 + 255)/256;         // 313
      gru_k<<<blocks, 256, 0, stream>>>(agg, hbuf, gk, rk, gb);
    }
  }
  hipMemcpyAsync(d_out, hbuf, (size_t)NN*UU*sizeof(float),
                 hipMemcpyDeviceToDevice, stream);
}

// Round 3
// 199.813 us; speedup vs baseline: 2.7185x; 1.3135x over previous
//
#include <hip/hip_runtime.h>
#include <math.h>

#define NN 5000      // nodes
#define NNP 5008     // padded to 16
#define NB 313       // NNP/16 node-tiles
#define NE 40000     // edges
#define UU 64        // hidden units
#define FE 16        // edge features
#define FEP 17       // +1 pseudo-feature for edge_bias
#define KD (FEP*UU)  // 1088
#define LDK (KD+8)   // padded LDS row (halfs): stride 548 dwords == 4 mod 32 -> conflict-free b128
#define NSTEPS 4
#define EMAX 1024    // max edges per 16-node block (mean 128; Poisson tail safe)
#define CH 8         // gather pipeline chunk

typedef _Float16 half8 __attribute__((ext_vector_type(8)));
typedef float f32x4 __attribute__((ext_vector_type(4)));

__device__ __forceinline__ float sigm(float x){ return 1.f/(1.f + __expf(-x)); }

// ---- build f16 weight tables: wb (64x1088 B^T), gkt/rkt (192x64 transposed) ----
#define WBN (UU*KD)        // 69632
#define GTN (192*64)       // 12288
__global__ void build_k(const float* __restrict__ ek, const float* __restrict__ eb,
                        const float* __restrict__ gk, const float* __restrict__ rk,
                        _Float16* __restrict__ wb, _Float16* __restrict__ gkt,
                        _Float16* __restrict__ rkt){
  int tid = blockIdx.x*blockDim.x + threadIdx.x;
  if (tid < WBN){
    int i = tid / KD, k = tid - i*KD;
    int f = k >> 6, j = k & 63;
    float v = (f < FE) ? ek[f*4096 + i*64 + j] : eb[i*64 + j];
    wb[tid] = (_Float16)v;
  } else if (tid < WBN + GTN){
    int r = tid - WBN; int n = r >> 6, k = r & 63;
    gkt[r] = (_Float16)gk[k*192 + n];
  } else if (tid < WBN + 2*GTN){
    int r = tid - WBN - GTN; int n = r >> 6, k = r & 63;
    rkt[r] = (_Float16)rk[k*192 + n];
  }
}

// ---- single-block: histogram + scan + scatter (LDS cursor). writes offs[NN+1], eid ----
__global__ __launch_bounds__(1024) void pre_k(const int* __restrict__ pair,
                                              int* __restrict__ offs, int* __restrict__ eid){
  __shared__ int cnt[NN];
  __shared__ int wsum[1024];
  int t = threadIdx.x;
  for (int i=t; i<NN; i+=1024) cnt[i] = 0;
  __syncthreads();
  for (int e=t; e<NE; e+=1024) atomicAdd(&cnt[pair[2*e]], 1);
  __syncthreads();
  const int PER = 5;                       // 1024*5 >= 5000
  int base = t*PER;
  int deg[PER]; int sum = 0;
  #pragma unroll
  for (int q=0;q<PER;++q){ int idx=base+q; int v=(idx<NN)?cnt[idx]:0; deg[q]=v; sum+=v; }
  wsum[t] = sum; __syncthreads();
  for (int off=1; off<1024; off<<=1){
    int v = (t>=off) ? wsum[t-off] : 0;
    __syncthreads();
    wsum[t] += v;
    __syncthreads();
  }
  int run = wsum[t] - sum;
  #pragma unroll
  for (int q=0;q<PER;++q){ int idx=base+q;
    if (idx<NN){ cnt[idx]=run; offs[idx]=run; run+=deg[q]; } }
  if (t==0) offs[NN] = NE;
  __syncthreads();
  for (int e=t; e<NE; e+=1024){ int pos = atomicAdd(&cnt[pair[2*e]], 1); eid[pos] = e; }
}

// deterministic order: insertion-sort each node's sublist
__global__ void sortsub_k(const int* __restrict__ offs, int* __restrict__ eid){
  int v = blockIdx.x*blockDim.x + threadIdx.x;
  if (v >= NN) return;
  int b = offs[v], e = offs[v+1];
  for (int i=b+1; i<e; ++i){
    int key = eid[i]; int j = i-1;
    while (j>=b && eid[j]>key){ eid[j+1]=eid[j]; --j; }
    eid[j+1] = key;
  }
}

// ---- fused step: gather(LDS G) -> MFMA agg -> MFMA GRU -> h_out ----
__global__ __launch_bounds__(256) void step_k(const float* __restrict__ h_in,
        float* __restrict__ h_out,
        const int* __restrict__ pair, const float* __restrict__ ef,
        const int* __restrict__ offs, const int* __restrict__ eid,
        const _Float16* __restrict__ wb, const _Float16* __restrict__ gkt,
        const _Float16* __restrict__ rkt, const float* __restrict__ gb){
  __shared__ _Float16 Gs[16*LDK];          // 35072 B
  __shared__ _Float16 aggT[16*72];         // 2304 B (stride 36 dw == 4 mod 32)
  __shared__ _Float16 hT[16*72];           // 2304 B
  __shared__ int esrc[EMAX];
  __shared__ int enbr[EMAX];
  __shared__ int eedg[EMAX];

  int tid = threadIdx.x;
  int w = tid >> 6, lane = tid & 63;
  int r16 = lane & 15, kh = lane >> 4;
  int vb = blockIdx.x * 16;

  // zero G tile (int4 stores)
  {
    int4* gz = (int4*)Gs;
    #pragma unroll
    for (int i=0;i<9;++i){ int idx = tid + i*256; if (idx < (16*LDK*2)/16) gz[idx] = make_int4(0,0,0,0); }
  }
  // stage edge list for this block's 16 nodes
  int ebase = offs[vb];
  int vtop  = (vb+16 < NN) ? vb+16 : NN;
  int ecnt  = offs[vtop] - ebase;
  for (int i=tid; i<ecnt; i+=256){
    int e = eid[ebase + i];
    int2 pr = *(const int2*)(pair + 2*e);
    esrc[i] = pr.x - vb; enbr[i] = pr.y; eedg[i] = e;
  }
  // stage own h tile (f16) for the GRU recurrent matmul
  for (int i=tid; i<16*64; i+=256){
    int lv = i >> 6, j = i & 63; int v = vb + lv;
    float hv = (v < NN) ? h_in[(size_t)v*64 + j] : 0.f;
    hT[lv*72 + j] = (_Float16)hv;
  }
  __syncthreads();

  // ---- gather: wave w accumulates features f0..f0+3 (+bias row for w==3) ----
  {
    int f0 = w*4;
    float g0=0.f,g1=0.f,g2=0.f,g3=0.f,gB=0.f;
    int cur = 0;
    float  hjA[CH], hjB[CH];
    float4 efA[CH], efB[CH];

#define LOADC(HJ,EF4,C0) { _Pragma("unroll") \
    for (int q=0;q<CH;++q){ int i=(C0)+q; \
      if (i<ecnt){ int nb=enbr[i]; int e=eedg[i]; \
        HJ[q] = h_in[(size_t)nb*64 + lane]; \
        EF4[q] = *(const float4*)(ef + (size_t)e*16 + f0); } } }
#define FLUSHG() { \
      Gs[cur*LDK + (f0+0)*64 + lane] = (_Float16)g0; \
      Gs[cur*LDK + (f0+1)*64 + lane] = (_Float16)g1; \
      Gs[cur*LDK + (f0+2)*64 + lane] = (_Float16)g2; \
      Gs[cur*LDK + (f0+3)*64 + lane] = (_Float16)g3; \
      if (w==3) Gs[cur*LDK + 16*64 + lane] = (_Float16)gB; }
#define PROCC(HJ,EF4,C0) { _Pragma("unroll") \
    for (int q=0;q<CH;++q){ int i=(C0)+q; \
      if (i<ecnt){ int ls = esrc[i]; \
        if (ls != cur){ FLUSHG(); g0=0.f;g1=0.f;g2=0.f;g3=0.f;gB=0.f; cur=ls; } \
        g0 = fmaf(EF4[q].x, HJ[q], g0); g1 = fmaf(EF4[q].y, HJ[q], g1); \
        g2 = fmaf(EF4[q].z, HJ[q], g2); g3 = fmaf(EF4[q].w, HJ[q], g3); \
        if (w==3) gB += HJ[q]; } } }

    LOADC(hjA, efA, 0)
    for (int c0=0; c0<ecnt; c0+=2*CH){
      LOADC(hjB, efB, c0+CH)
      PROCC(hjA, efA, c0)
      LOADC(hjA, efA, c0+2*CH)
      PROCC(hjB, efB, c0+CH)
    }
    if (ecnt > 0) FLUSHG();
  }
  __syncthreads();

  // ---- agg matmul: wave w computes 16-col fragment w over 34 k-steps ----
  f32x4 acc = {0.f,0.f,0.f,0.f};
  {
    const _Float16* ap = Gs + r16*LDK + kh*8;
    const _Float16* bp = wb + (size_t)(w*16 + r16)*KD + kh*8;
    #pragma unroll 2
    for (int k0=0; k0<KD; k0+=32){
      half8 a = *(const half8*)(ap + k0);
      half8 b = *(const half8*)(bp + k0);
      acc = __builtin_amdgcn_mfma_f32_16x16x32_f16(a, b, acc, 0, 0, 0);
    }
  }
  // stage agg tile as f16 (C layout: row = kh*4+r, col = w*16+r16)
  #pragma unroll
  for (int r=0;r<4;++r) aggT[(kh*4+r)*72 + w*16 + r16] = (_Float16)acc[r];
  __syncthreads();

  // ---- GRU via MFMA: wave w owns unit cols uw = w*16+r16 ----
  {
    int uw = w*16 + r16;
    const _Float16* az = aggT + r16*72 + kh*8;
    const _Float16* ah = hT   + r16*72 + kh*8;
    f32x4 mxz={0.f,0.f,0.f,0.f}, mxr=mxz, mxh=mxz, mhz=mxz, mhr=mxz, mhh=mxz;
    #pragma unroll
    for (int ks=0; ks<2; ++ks){
      half8 aa = *(const half8*)(az + ks*32);
      half8 hh = *(const half8*)(ah + ks*32);
      half8 bz = *(const half8*)(gkt + (size_t)(      uw)*64 + ks*32 + kh*8);
      half8 br = *(const half8*)(gkt + (size_t)( 64 + uw)*64 + ks*32 + kh*8);
      half8 bh = *(const half8*)(gkt + (size_t)(128 + uw)*64 + ks*32 + kh*8);
      half8 cz = *(const half8*)(rkt + (size_t)(      uw)*64 + ks*32 + kh*8);
      half8 cr = *(const half8*)(rkt + (size_t)( 64 + uw)*64 + ks*32 + kh*8);
      half8 ch = *(const half8*)(rkt + (size_t)(128 + uw)*64 + ks*32 + kh*8);
      mxz = __builtin_amdgcn_mfma_f32_16x16x32_f16(aa, bz, mxz, 0,0,0);
      mxr = __builtin_amdgcn_mfma_f32_16x16x32_f16(aa, br, mxr, 0,0,0);
      mxh = __builtin_amdgcn_mfma_f32_16x16x32_f16(aa, bh, mxh, 0,0,0);
      mhz = __builtin_amdgcn_mfma_f32_16x16x32_f16(hh, cz, mhz, 0,0,0);
      mhr = __builtin_amdgcn_mfma_f32_16x16x32_f16(hh, cr, mhr, 0,0,0);
      mhh = __builtin_amdgcn_mfma_f32_16x16x32_f16(hh, ch, mhh, 0,0,0);
    }
    float b0z = gb[uw],      b0r = gb[64+uw],  b0h = gb[128+uw];
    float b1z = gb[192+uw],  b1r = gb[256+uw], b1h = gb[320+uw];
    #pragma unroll
    for (int r=0;r<4;++r){
      int row = vb + kh*4 + r;
      if (row < NN){
        float z  = sigm(mxz[r] + b0z + mhz[r] + b1z);
        float rr = sigm(mxr[r] + b0r + mhr[r] + b1r);
        float hc = tanhf(mxh[r] + b0h + rr*(mhh[r] + b1h));
        float hold = h_in[(size_t)row*64 + uw];
        h_out[(size_t)row*64 + uw] = z*hold + (1.f - z)*hc;
      }
    }
  }
}

extern "C" void kernel_launch(void* const* d_in, const int* in_sizes, int n_in,
                              void* d_out, int out_size, void* d_ws, size_t ws_size,
                              hipStream_t stream){
  const float* nodef = (const float*)d_in[0];
  const float* edgef = (const float*)d_in[1];
  const int*   pair  = (const int*)  d_in[2];
  const float* ek    = (const float*)d_in[3];
  const float* ebias = (const float*)d_in[4];
  const float* gk    = (const float*)d_in[5];
  const float* rk    = (const float*)d_in[6];
  const float* gb    = (const float*)d_in[7];

  char* ws = (char*)d_ws;
  size_t o = 0;
  auto carve = [&](size_t bytes)->char*{
    char* p = ws + o; o = (o + bytes + 255) & ~255ULL; return p; };
  int*      offs = (int*)     carve((NN+1)*sizeof(int));
  int*      eid  = (int*)     carve(NE*sizeof(int));
  _Float16* wb   = (_Float16*)carve((size_t)WBN*sizeof(_Float16));
  _Float16* gkt  = (_Float16*)carve((size_t)GTN*sizeof(_Float16));
  _Float16* rkt  = (_Float16*)carve((size_t)GTN*sizeof(_Float16));
  float*    hA   = (float*)   carve((size_t)NN*UU*sizeof(float));
  float*    hB   = (float*)   carve((size_t)NN*UU*sizeof(float));

  build_k <<<(WBN+2*GTN+255)/256, 256, 0, stream>>>(ek, ebias, gk, rk, wb, gkt, rkt);
  pre_k   <<<1, 1024, 0, stream>>>(pair, offs, eid);
  sortsub_k<<<(NN+255)/256, 256, 0, stream>>>(offs, eid);

  const float* hin = nodef;
  for (int s=0; s<NSTEPS; ++s){
    float* hout = (s == NSTEPS-1) ? (float*)d_out : ((s & 1) ? hB : hA);
    step_k<<<NB, 256, 0, stream>>>(hin, hout, pair, edgef, offs, eid,
                                   wb, gkt, rkt, gb);
    hin = hout;
  }
}

// Round 4
// 183.926 us; speedup vs baseline: 2.9534x; 1.0864x over previous
//
#include <hip/hip_runtime.h>
#include <math.h>

#define NN 5000      // nodes
#define NE 40000     // edges
#define UU 64        // hidden units
#define FE 16        // edge features
#define FEP 17       // +1 pseudo-feature for edge_bias
#define KD (FEP*UU)  // 1088
#define LDK (KD+8)   // padded LDS row (halfs)
#define NSTEPS 4
#define NT 4         // nodes per step-tile (5000 % 4 == 0)
#define NB (NN/NT)   // 1250 blocks
#define EMAX 128     // max edges per 4-node tile (mean 32, sd 5.7 -> 17 sigma)
#define CH 8         // gather pipeline chunk

typedef _Float16 half8 __attribute__((ext_vector_type(8)));
typedef float f32x4 __attribute__((ext_vector_type(4)));

__device__ __forceinline__ float sigm(float x){ return 1.f/(1.f + __expf(-x)); }

// ---- build f16 weight tables: wb (64x1088 B^T), gkt/rkt (192x64 transposed) ----
#define WBN (UU*KD)        // 69632
#define GTN (192*64)       // 12288
__global__ void build_k(const float* __restrict__ ek, const float* __restrict__ eb,
                        const float* __restrict__ gk, const float* __restrict__ rk,
                        _Float16* __restrict__ wb, _Float16* __restrict__ gkt,
                        _Float16* __restrict__ rkt){
  int tid = blockIdx.x*blockDim.x + threadIdx.x;
  if (tid < WBN){
    int i = tid / KD, k = tid - i*KD;
    int f = k >> 6, j = k & 63;
    float v = (f < FE) ? ek[f*4096 + i*64 + j] : eb[i*64 + j];
    wb[tid] = (_Float16)v;
  } else if (tid < WBN + GTN){
    int r = tid - WBN; int n = r >> 6, k = r & 63;
    gkt[r] = (_Float16)gk[k*192 + n];
  } else if (tid < WBN + 2*GTN){
    int r = tid - WBN - GTN; int n = r >> 6, k = r & 63;
    rkt[r] = (_Float16)rk[k*192 + n];
  }
}

// ---- parallel preprocessing (round-1 style) ----
__global__ void hist_k(const int* __restrict__ pair, int* __restrict__ hist){
  int e = blockIdx.x*blockDim.x + threadIdx.x;
  if (e < NE) atomicAdd(&hist[pair[2*e]], 1);
}

__global__ void scan_k(int* __restrict__ offs, int* __restrict__ cursor){
  __shared__ int s[1024];
  const int PER = 5;
  int t = threadIdx.x;
  int base = t*PER;
  int loc[PER]; int sum = 0;
  #pragma unroll
  for (int q=0;q<PER;++q){ int idx = base+q; int v = (idx<NN)?offs[idx]:0; loc[q]=v; sum+=v; }
  s[t] = sum; __syncthreads();
  for (int off=1; off<1024; off<<=1){
    int v = (t>=off) ? s[t-off] : 0;
    __syncthreads();
    s[t] += v;
    __syncthreads();
  }
  int run = s[t] - sum;
  #pragma unroll
  for (int q=0;q<PER;++q){ int idx = base+q;
    if (idx<NN){ offs[idx]=run; cursor[idx]=run; run+=loc[q]; } }
  if (t==1023) offs[NN] = run;
}

__global__ void scatter_k(const int* __restrict__ pair, int* __restrict__ cursor,
                          int* __restrict__ eid){
  int e = blockIdx.x*blockDim.x + threadIdx.x;
  if (e < NE){ int pos = atomicAdd(&cursor[pair[2*e]], 1); eid[pos] = e; }
}

// deterministic accumulation order: insertion-sort each node's sublist
__global__ void sortsub_k(const int* __restrict__ offs, int* __restrict__ eid){
  int v = blockIdx.x*blockDim.x + threadIdx.x;
  if (v >= NN) return;
  int b = offs[v], e = offs[v+1];
  for (int i=b+1; i<e; ++i){
    int key = eid[i]; int j = i-1;
    while (j>=b && eid[j]>key){ eid[j+1]=eid[j]; --j; }
    eid[j+1] = key;
  }
}

// ---- fused step, 4-node tile: gather(1 wave/node) -> MFMA agg -> MFMA GRU ----
__global__ __launch_bounds__(256) void step_k(const float* __restrict__ h_in,
        float* __restrict__ h_out,
        const int* __restrict__ pair, const float* __restrict__ ef,
        const int* __restrict__ offs, const int* __restrict__ eid,
        const _Float16* __restrict__ wb, const _Float16* __restrict__ gkt,
        const _Float16* __restrict__ rkt, const float* __restrict__ gb){
  __shared__ _Float16 Gs[NT*LDK];      // 8768 B
  __shared__ float    eef[EMAX*FE];    // 8192 B
  __shared__ int      enbr[EMAX];      // 512 B
  __shared__ _Float16 aggT[NT*72];     // 576 B
  __shared__ _Float16 hT[NT*72];       // 576 B

  int tid = threadIdx.x;
  int w = tid >> 6, lane = tid & 63;
  int r16 = lane & 15, kh = lane >> 4;
  int vb = blockIdx.x * NT;

  int ebase = offs[vb];
  int ecnt  = offs[vb + NT] - ebase;

  // stage neighbor ids + edge features (f32) + own h tile (f16)
  for (int i=tid; i<ecnt; i+=256) enbr[i] = pair[2*eid[ebase + i] + 1];
  for (int idx=tid; idx<ecnt*FE; idx+=256){
    int i = idx >> 4, f = idx & 15;
    eef[idx] = ef[(size_t)eid[ebase + i]*FE + f];
  }
  hT[w*72 + lane] = (_Float16)h_in[(size_t)(vb + w)*64 + lane];
  __syncthreads();

  // ---- gather: wave w owns node vb+w entirely (17 features, lane = unit) ----
  {
    int myb = offs[vb + w]     - ebase;
    int mye = offs[vb + w + 1] - ebase;
    float g[FEP];
    #pragma unroll
    for (int f=0;f<FEP;++f) g[f] = 0.f;
    for (int c0=myb; c0<mye; c0+=CH){
      float hj[CH];
      #pragma unroll
      for (int q=0;q<CH;++q){ int i=c0+q;
        hj[q] = (i<mye) ? h_in[(size_t)enbr[i]*64 + lane] : 0.f; }
      #pragma unroll
      for (int q=0;q<CH;++q){ int i=c0+q;
        if (i<mye){
          const float* er = &eef[i*FE];
          #pragma unroll
          for (int f=0;f<FE;++f) g[f] = fmaf(er[f], hj[q], g[f]);
          g[FE] += hj[q];
        } }
    }
    #pragma unroll
    for (int f=0;f<FEP;++f) Gs[w*LDK + f*64 + lane] = (_Float16)g[f];
  }
  __syncthreads();

  // ---- agg matmul: wave w = cols w*16..w*16+15; A rows 0-3 valid ----
  f32x4 acc = {0.f,0.f,0.f,0.f};
  {
    const _Float16* ap = Gs + (r16 & 3)*LDK + kh*8;
    const _Float16* bp = wb + (size_t)(w*16 + r16)*KD + kh*8;
    #pragma unroll 2
    for (int k0=0; k0<KD; k0+=32){
      half8 a = *(const half8*)(ap + k0);
      half8 b = *(const half8*)(bp + k0);
      acc = __builtin_amdgcn_mfma_f32_16x16x32_f16(a, b, acc, 0, 0, 0);
    }
  }
  if (kh == 0){            // C rows 0-3 live in kh==0 lanes (row = kh*4+r)
    #pragma unroll
    for (int r=0;r<4;++r) aggT[r*72 + w*16 + r16] = (_Float16)acc[r];
  }
  __syncthreads();

  // ---- GRU via MFMA: wave w owns units uw = w*16 + r16 ----
  {
    int uw = w*16 + r16;
    const _Float16* az = aggT + (r16 & 3)*72 + kh*8;
    const _Float16* ah = hT   + (r16 & 3)*72 + kh*8;
    f32x4 mxz={0.f,0.f,0.f,0.f}, mxr=mxz, mxh=mxz, mhz=mxz, mhr=mxz, mhh=mxz;
    #pragma unroll
    for (int ks=0; ks<2; ++ks){
      half8 aa = *(const half8*)(az + ks*32);
      half8 hh = *(const half8*)(ah + ks*32);
      half8 bz = *(const half8*)(gkt + (size_t)(      uw)*64 + ks*32 + kh*8);
      half8 br = *(const half8*)(gkt + (size_t)( 64 + uw)*64 + ks*32 + kh*8);
      half8 bh = *(const half8*)(gkt + (size_t)(128 + uw)*64 + ks*32 + kh*8);
      half8 cz = *(const half8*)(rkt + (size_t)(      uw)*64 + ks*32 + kh*8);
      half8 cr = *(const half8*)(rkt + (size_t)( 64 + uw)*64 + ks*32 + kh*8);
      half8 ch = *(const half8*)(rkt + (size_t)(128 + uw)*64 + ks*32 + kh*8);
      mxz = __builtin_amdgcn_mfma_f32_16x16x32_f16(aa, bz, mxz, 0,0,0);
      mxr = __builtin_amdgcn_mfma_f32_16x16x32_f16(aa, br, mxr, 0,0,0);
      mxh = __builtin_amdgcn_mfma_f32_16x16x32_f16(aa, bh, mxh, 0,0,0);
      mhz = __builtin_amdgcn_mfma_f32_16x16x32_f16(hh, cz, mhz, 0,0,0);
      mhr = __builtin_amdgcn_mfma_f32_16x16x32_f16(hh, cr, mhr, 0,0,0);
      mhh = __builtin_amdgcn_mfma_f32_16x16x32_f16(hh, ch, mhh, 0,0,0);
    }
    if (kh == 0){
      float b0z = gb[uw],      b0r = gb[64+uw],  b0h = gb[128+uw];
      float b1z = gb[192+uw],  b1r = gb[256+uw], b1h = gb[320+uw];
      #pragma unroll
      for (int r=0;r<4;++r){
        int row = vb + r;
        float z  = sigm(mxz[r] + b0z + mhz[r] + b1z);
        float rr = sigm(mxr[r] + b0r + mhr[r] + b1r);
        float hc = tanhf(mxh[r] + b0h + rr*(mhh[r] + b1h));
        float hold = h_in[(size_t)row*64 + uw];
        h_out[(size_t)row*64 + uw] = z*hold + (1.f - z)*hc;
      }
    }
  }
}

extern "C" void kernel_launch(void* const* d_in, const int* in_sizes, int n_in,
                              void* d_out, int out_size, void* d_ws, size_t ws_size,
                              hipStream_t stream){
  const float* nodef = (const float*)d_in[0];
  const float* edgef = (const float*)d_in[1];
  const int*   pair  = (const int*)  d_in[2];
  const float* ek    = (const float*)d_in[3];
  const float* ebias = (const float*)d_in[4];
  const float* gk    = (const float*)d_in[5];
  const float* rk    = (const float*)d_in[6];
  const float* gb    = (const float*)d_in[7];

  char* ws = (char*)d_ws;
  size_t o = 0;
  auto carve = [&](size_t bytes)->char*{
    char* p = ws + o; o = (o + bytes + 255) & ~255ULL; return p; };
  int*      offs   = (int*)     carve((NN+1)*sizeof(int));
  int*      cursor = (int*)     carve(NN*sizeof(int));
  int*      eid    = (int*)     carve(NE*sizeof(int));
  _Float16* wb     = (_Float16*)carve((size_t)WBN*sizeof(_Float16));
  _Float16* gkt    = (_Float16*)carve((size_t)GTN*sizeof(_Float16));
  _Float16* rkt    = (_Float16*)carve((size_t)GTN*sizeof(_Float16));
  float*    hA     = (float*)   carve((size_t)NN*UU*sizeof(float));
  float*    hB     = (float*)   carve((size_t)NN*UU*sizeof(float));

  hipMemsetAsync(offs, 0, (NN+1)*sizeof(int), stream);
  build_k  <<<(WBN+2*GTN+255)/256, 256, 0, stream>>>(ek, ebias, gk, rk, wb, gkt, rkt);
  hist_k   <<<(NE+255)/256, 256, 0, stream>>>(pair, offs);
  scan_k   <<<1, 1024, 0, stream>>>(offs, cursor);
  scatter_k<<<(NE+255)/256, 256, 0, stream>>>(pair, cursor, eid);
  sortsub_k<<<(NN+255)/256, 256, 0, stream>>>(offs, eid);

  const float* hin = nodef;
  for (int s=0; s<NSTEPS; ++s){
    float* hout = (s == NSTEPS-1) ? (float*)d_out : ((s & 1) ? hB : hA);
    step_k<<<NB, 256, 0, stream>>>(hin, hout, pair, edgef, offs, eid,
                                   wb, gkt, rkt, gb);
    hin = hout;
  }
}

// Round 5
// 143.340 us; speedup vs baseline: 3.7896x; 1.2831x over previous
//
#include <hip/hip_runtime.h>
#include <math.h>

#define NN 5000      // nodes
#define NE 40000     // edges
#define UU 64        // hidden units
#define FE 16        // edge features
#define FEP 17       // +1 pseudo-feature for edge_bias
#define KD (FEP*UU)  // 1088
#define LDK (KD+8)   // padded LDS row (halfs)
#define NSTEPS 4
#define NT 8         // nodes per step-tile (5000 % 8 == 0)
#define NB (NN/NT)   // 625 blocks
#define EMAX 256     // max edges per 8-node tile (mean 64, sd 8 -> 24 sigma)
#define CH 8         // gather pipeline chunk

typedef _Float16 half8 __attribute__((ext_vector_type(8)));
typedef float f32x4 __attribute__((ext_vector_type(4)));

__device__ __forceinline__ float sigm(float x){ return 1.f/(1.f + __expf(-x)); }
__device__ __forceinline__ int rfl(int x){ return __builtin_amdgcn_readfirstlane(x); }

// ---- build f16 weight tables + zero offs (replaces hipMemsetAsync dispatch) ----
#define WBN (UU*KD)        // 69632
#define GTN (192*64)       // 12288
__global__ void build_k(const float* __restrict__ ek, const float* __restrict__ eb,
                        const float* __restrict__ gk, const float* __restrict__ rk,
                        _Float16* __restrict__ wb, _Float16* __restrict__ gkt,
                        _Float16* __restrict__ rkt, int* __restrict__ offs){
  int tid = blockIdx.x*blockDim.x + threadIdx.x;
  if (tid <= NN) offs[tid] = 0;            // runs before hist_k on same stream
  if (tid < WBN){
    int i = tid / KD, k = tid - i*KD;
    int f = k >> 6, j = k & 63;
    float v = (f < FE) ? ek[f*4096 + i*64 + j] : eb[i*64 + j];
    wb[tid] = (_Float16)v;
  } else if (tid < WBN + GTN){
    int r = tid - WBN; int n = r >> 6, k = r & 63;
    gkt[r] = (_Float16)gk[k*192 + n];
  } else if (tid < WBN + 2*GTN){
    int r = tid - WBN - GTN; int n = r >> 6, k = r & 63;
    rkt[r] = (_Float16)rk[k*192 + n];
  }
}

// ---- parallel preprocessing ----
__global__ void hist_k(const int* __restrict__ pair, int* __restrict__ hist){
  int e = blockIdx.x*blockDim.x + threadIdx.x;
  if (e < NE) atomicAdd(&hist[pair[2*e]], 1);
}

__global__ void scan_k(int* __restrict__ offs, int* __restrict__ cursor){
  __shared__ int s[1024];
  const int PER = 5;
  int t = threadIdx.x;
  int base = t*PER;
  int loc[PER]; int sum = 0;
  #pragma unroll
  for (int q=0;q<PER;++q){ int idx = base+q; int v = (idx<NN)?offs[idx]:0; loc[q]=v; sum+=v; }
  s[t] = sum; __syncthreads();
  for (int off=1; off<1024; off<<=1){
    int v = (t>=off) ? s[t-off] : 0;
    __syncthreads();
    s[t] += v;
    __syncthreads();
  }
  int run = s[t] - sum;
  #pragma unroll
  for (int q=0;q<PER;++q){ int idx = base+q;
    if (idx<NN){ offs[idx]=run; cursor[idx]=run; run+=loc[q]; } }
  if (t==1023) offs[NN] = run;
}

__global__ void scatter_k(const int* __restrict__ pair, int* __restrict__ cursor,
                          int* __restrict__ eid){
  int e = blockIdx.x*blockDim.x + threadIdx.x;
  if (e < NE){ int pos = atomicAdd(&cursor[pair[2*e]], 1); eid[pos] = e; }
}

// deterministic accumulation order: insertion-sort each node's sublist
__global__ void sortsub_k(const int* __restrict__ offs, int* __restrict__ eid){
  int v = blockIdx.x*blockDim.x + threadIdx.x;
  if (v >= NN) return;
  int b = offs[v], e = offs[v+1];
  for (int i=b+1; i<e; ++i){
    int key = eid[i]; int j = i-1;
    while (j>=b && eid[j]>key){ eid[j+1]=eid[j]; --j; }
    eid[j+1] = key;
  }
}

// ---- fused step, 8-node tile, 8 waves: gather(1 wave/node) -> MFMA agg -> MFMA GRU ----
__global__ __launch_bounds__(512) void step_k(const float* __restrict__ h_in,
        float* __restrict__ h_out,
        const int* __restrict__ pair, const float* __restrict__ ef,
        const int* __restrict__ offs, const int* __restrict__ eid,
        const _Float16* __restrict__ wb, const _Float16* __restrict__ gkt,
        const _Float16* __restrict__ rkt, const float* __restrict__ gb){
  __shared__ _Float16 Gs[NT*LDK];      // 17536 B
  __shared__ int      enbr[EMAX];      // 1024 B
  __shared__ int      eedg[EMAX];      // 1024 B
  __shared__ _Float16 aggT[NT*72];     // 1152 B
  __shared__ _Float16 hT[NT*72];       // 1152 B

  int tid = threadIdx.x;
  int w = tid >> 6, lane = tid & 63;
  int r16 = lane & 15, kh = lane >> 4;
  int vb = blockIdx.x * NT;

  int ebase = offs[vb];
  int ecnt  = offs[vb + NT] - ebase;

  // stage neighbor/edge ids + own h tile (f16)
  for (int i=tid; i<ecnt; i+=512){
    int e = eid[ebase + i];
    enbr[i] = pair[2*e + 1];
    eedg[i] = e;
  }
  hT[w*72 + lane] = (_Float16)h_in[(size_t)(vb + w)*64 + lane];
  __syncthreads();

  // ---- gather: wave w owns node vb+w (17 features, lane = unit) ----
  {
    int myb = offs[vb + w]     - ebase;
    int mye = offs[vb + w + 1] - ebase;
    float g[FEP];
    #pragma unroll
    for (int f=0;f<FEP;++f) g[f] = 0.f;
    for (int c0=myb; c0<mye; c0+=CH){
      float hj[CH];
      #pragma unroll
      for (int q=0;q<CH;++q){ int i=c0+q;
        if (i<mye){ int nb = rfl(enbr[i]); hj[q] = h_in[(size_t)nb*64 + lane]; }
        else hj[q] = 0.f; }
      #pragma unroll
      for (int q=0;q<CH;++q){ int i=c0+q;
        if (i<mye){
          int e = rfl(eedg[i]);
          const float4* er = (const float4*)(ef + (size_t)e*FE);
          float4 e0 = er[0], e1 = er[1], e2 = er[2], e3 = er[3];
          g[ 0]=fmaf(e0.x,hj[q],g[ 0]); g[ 1]=fmaf(e0.y,hj[q],g[ 1]);
          g[ 2]=fmaf(e0.z,hj[q],g[ 2]); g[ 3]=fmaf(e0.w,hj[q],g[ 3]);
          g[ 4]=fmaf(e1.x,hj[q],g[ 4]); g[ 5]=fmaf(e1.y,hj[q],g[ 5]);
          g[ 6]=fmaf(e1.z,hj[q],g[ 6]); g[ 7]=fmaf(e1.w,hj[q],g[ 7]);
          g[ 8]=fmaf(e2.x,hj[q],g[ 8]); g[ 9]=fmaf(e2.y,hj[q],g[ 9]);
          g[10]=fmaf(e2.z,hj[q],g[10]); g[11]=fmaf(e2.w,hj[q],g[11]);
          g[12]=fmaf(e3.x,hj[q],g[12]); g[13]=fmaf(e3.y,hj[q],g[13]);
          g[14]=fmaf(e3.z,hj[q],g[14]); g[15]=fmaf(e3.w,hj[q],g[15]);
          g[16] += hj[q];
        } }
    }
    #pragma unroll
    for (int f=0;f<FEP;++f) Gs[w*LDK + f*64 + lane] = (_Float16)g[f];
  }
  __syncthreads();

  // ---- agg matmul: waves 0-3, wave w = cols w*16..w*16+15; A rows 0-7 valid ----
  if (w < 4){
    f32x4 acc = {0.f,0.f,0.f,0.f};
    const _Float16* ap = Gs + (r16 & 7)*LDK + kh*8;
    const _Float16* bp = wb + (size_t)(w*16 + r16)*KD + kh*8;
    #pragma unroll 2
    for (int k0=0; k0<KD; k0+=32){
      half8 a = *(const half8*)(ap + k0);
      half8 b = *(const half8*)(bp + k0);
      acc = __builtin_amdgcn_mfma_f32_16x16x32_f16(a, b, acc, 0, 0, 0);
    }
    if (kh < 2){           // C rows 0-7 live in kh 0,1 (row = kh*4+r)
      #pragma unroll
      for (int r=0;r<4;++r) aggT[(kh*4+r)*72 + w*16 + r16] = (_Float16)acc[r];
    }
  }
  __syncthreads();

  // ---- GRU via MFMA: waves 0-3, wave w owns units uw = w*16 + r16 ----
  if (w < 4){
    int uw = w*16 + r16;
    const _Float16* az = aggT + (r16 & 7)*72 + kh*8;
    const _Float16* ah = hT   + (r16 & 7)*72 + kh*8;
    f32x4 mxz={0.f,0.f,0.f,0.f}, mxr=mxz, mxh=mxz, mhz=mxz, mhr=mxz, mhh=mxz;
    #pragma unroll
    for (int ks=0; ks<2; ++ks){
      half8 aa = *(const half8*)(az + ks*32);
      half8 hh = *(const half8*)(ah + ks*32);
      half8 bz = *(const half8*)(gkt + (size_t)(      uw)*64 + ks*32 + kh*8);
      half8 br = *(const half8*)(gkt + (size_t)( 64 + uw)*64 + ks*32 + kh*8);
      half8 bh = *(const half8*)(gkt + (size_t)(128 + uw)*64 + ks*32 + kh*8);
      half8 cz = *(const half8*)(rkt + (size_t)(      uw)*64 + ks*32 + kh*8);
      half8 cr = *(const half8*)(rkt + (size_t)( 64 + uw)*64 + ks*32 + kh*8);
      half8 ch = *(const half8*)(rkt + (size_t)(128 + uw)*64 + ks*32 + kh*8);
      mxz = __builtin_amdgcn_mfma_f32_16x16x32_f16(aa, bz, mxz, 0,0,0);
      mxr = __builtin_amdgcn_mfma_f32_16x16x32_f16(aa, br, mxr, 0,0,0);
      mxh = __builtin_amdgcn_mfma_f32_16x16x32_f16(aa, bh, mxh, 0,0,0);
      mhz = __builtin_amdgcn_mfma_f32_16x16x32_f16(hh, cz, mhz, 0,0,0);
      mhr = __builtin_amdgcn_mfma_f32_16x16x32_f16(hh, cr, mhr, 0,0,0);
      mhh = __builtin_amdgcn_mfma_f32_16x16x32_f16(hh, ch, mhh, 0,0,0);
    }
    if (kh < 2){
      float b0z = gb[uw],      b0r = gb[64+uw],  b0h = gb[128+uw];
      float b1z = gb[192+uw],  b1r = gb[256+uw], b1h = gb[320+uw];
      #pragma unroll
      for (int r=0;r<4;++r){
        int row = vb + kh*4 + r;
        float z  = sigm(mxz[r] + b0z + mhz[r] + b1z);
        float rr = sigm(mxr[r] + b0r + mhr[r] + b1r);
        float hc = tanhf(mxh[r] + b0h + rr*(mhh[r] + b1h));
        float hold = h_in[(size_t)row*64 + uw];
        h_out[(size_t)row*64 + uw] = z*hold + (1.f - z)*hc;
      }
    }
  }
}

extern "C" void kernel_launch(void* const* d_in, const int* in_sizes, int n_in,
                              void* d_out, int out_size, void* d_ws, size_t ws_size,
                              hipStream_t stream){
  const float* nodef = (const float*)d_in[0];
  const float* edgef = (const float*)d_in[1];
  const int*   pair  = (const int*)  d_in[2];
  const float* ek    = (const float*)d_in[3];
  const float* ebias = (const float*)d_in[4];
  const float* gk    = (const float*)d_in[5];
  const float* rk    = (const float*)d_in[6];
  const float* gb    = (const float*)d_in[7];

  char* ws = (char*)d_ws;
  size_t o = 0;
  auto carve = [&](size_t bytes)->char*{
    char* p = ws + o; o = (o + bytes + 255) & ~255ULL; return p; };
  int*      offs   = (int*)     carve((NN+1)*sizeof(int));
  int*      cursor = (int*)     carve(NN*sizeof(int));
  int*      eid    = (int*)     carve(NE*sizeof(int));
  _Float16* wb     = (_Float16*)carve((size_t)WBN*sizeof(_Float16));
  _Float16* gkt    = (_Float16*)carve((size_t)GTN*sizeof(_Float16));
  _Float16* rkt    = (_Float16*)carve((size_t)GTN*sizeof(_Float16));
  float*    hA     = (float*)   carve((size_t)NN*UU*sizeof(float));
  float*    hB     = (float*)   carve((size_t)NN*UU*sizeof(float));

  build_k  <<<(WBN+2*GTN+255)/256, 256, 0, stream>>>(ek, ebias, gk, rk, wb, gkt, rkt, offs);
  hist_k   <<<(NE+255)/256, 256, 0, stream>>>(pair, offs);
  scan_k   <<<1, 1024, 0, stream>>>(offs, cursor);
  scatter_k<<<(NE+255)/256, 256, 0, stream>>>(pair, cursor, eid);
  sortsub_k<<<(NN+255)/256, 256, 0, stream>>>(offs, eid);

  const float* hin = nodef;
  for (int s=0; s<NSTEPS; ++s){
    float* hout = (s == NSTEPS-1) ? (float*)d_out : ((s & 1) ? hB : hA);
    step_k<<<NB, 512, 0, stream>>>(hin, hout, pair, edgef, offs, eid,
                                   wb, gkt, rkt, gb);
    hin = hout;
  }
}